// Round 9
// baseline (461.078 us; speedup 1.0000x reference)
//
#include <hip/hip_runtime.h>

// RadarRnn1: 4-layer tanh RNN (B=512,S=1024,IN=64,H=32) + per-step FC + softmax over S.
// R17: residue analysis across 9 rounds: total - rnn = ~205us constant, tracks
// kernel removals exactly => u0_kernel ~ 190us (never top-5, never measured;
// R8's "14us" was an estimate). Cause: u0 issues 512 broadcast ds_read_b128
// per thread (whole 8KB W per thread); LDS is ONE pipe per CU -> ~196Kcy/CU
// of DS serialization (~80+us) plus scattered 256B-stride global loads.
// Fix: 4 rows per thread (512 blocks x 256 thr x 4 rows). Each W broadcast
// read is reused by 4 row-accumulators: DS instrs/row drop 4x. acc[4][32] =
// 128 VGPR, statically indexed under full unroll; __launch_bounds__(256,1)
// unlocks the register budget. Per-row FP32 expression order identical to the
// proven kernel -> bit-identical u0 output.
// rnn_kernel: byte-identical to R16 (222us proven) for clean attribution.

#define BB 512
#define SS 1024
#define INF 64
#define HH 32
#define LL 4
#define KB 16  // ticks per barrier iteration

typedef __fp16 v2h __attribute__((ext_vector_type(2)));

__device__ __forceinline__ v2h bch(unsigned u) { return __builtin_bit_cast(v2h, u); }
__device__ __forceinline__ unsigned bcu(v2h h) { return __builtin_bit_cast(unsigned, h); }

template <int CTRL>
__device__ __forceinline__ float dpp_add(float v) {
  int y = __builtin_amdgcn_update_dpp(0, __float_as_int(v), CTRL, 0xF, 0xF, true);
  return v + __int_as_float(y);
}
template <int CTRL>
__device__ __forceinline__ float dpp_mov(float v) {
  int y = __builtin_amdgcn_update_dpp(0, __float_as_int(v), CTRL, 0xF, 0xF, true);
  return __int_as_float(y);
}

// tanh(a) = 1 - 2/(e^{2a}+1); e^{2a} = 2^(a * 2/ln2). v_exp + v_rcp + fma.
__device__ __forceinline__ float tanh_fast(float a) {
  const float e = __builtin_amdgcn_exp2f(a * 2.885390081777927f);
  const float r = __builtin_amdgcn_rcpf(e + 1.0f);
  return __builtin_fmaf(-2.0f, r, 1.0f);
}

// 16-half dot (ks-half): 8 fdot2 in 2 chains of depth 4.
__device__ __forceinline__ float dot16p(const v2h* w, const v2h* v) {
  float a = 0.f, c = 0.f;
#pragma unroll
  for (int j = 0; j < 4; ++j) {
    a = __builtin_amdgcn_fdot2(w[2 * j + 0], v[2 * j + 0], a, false);
    c = __builtin_amdgcn_fdot2(w[2 * j + 1], v[2 * j + 1], c, false);
  }
  return a + c;
}

// lgkmcnt-only barrier: drains LDS ops (cross-wave handoff) but leaves global
// loads/stores in flight (u0 prefetch, hfin stores).
#define BAR() asm volatile("s_waitcnt lgkmcnt(0)\n\ts_barrier" ::: "memory")

// ---------------- u0 = x @ W_ih0^T + (b_ih0 + b_hh0) ----------------
// R17: 4 rows/thread so each broadcast W ds_read feeds 4 accumulators.
__global__ __launch_bounds__(256, 1) void u0_kernel(
    const float* __restrict__ x, const float* __restrict__ W_ih0,
    const float* __restrict__ b_ih, const float* __restrict__ b_hh,
    float* __restrict__ u0) {
  __shared__ float Wl[HH * INF];  // [u][k]
  __shared__ float bl[HH];
  const int tid = threadIdx.x;
  {
    const float4* src = (const float4*)W_ih0;
    float4* dst = (float4*)Wl;
    dst[tid] = src[tid];
    dst[tid + 256] = src[tid + 256];
    if (tid < HH) bl[tid] = b_ih[tid] + b_hh[tid];
  }
  __syncthreads();

  // 512 blocks x 256 threads x 4 rows = 524288 rows; thread's rows contiguous
  const size_t row0 = (size_t)blockIdx.x * 1024 + (size_t)tid * 4;
  const float4* xr = (const float4*)(x + row0 * INF);  // 64 float4, 1KB/thread
  float acc[4][HH];
#pragma unroll
  for (int r = 0; r < 4; ++r)
#pragma unroll
    for (int u = 0; u < HH; ++u) acc[r][u] = bl[u];
#pragma unroll 2
  for (int kc = 0; kc < 16; ++kc) {
    const float4 xv0 = xr[kc];
    const float4 xv1 = xr[16 + kc];
    const float4 xv2 = xr[32 + kc];
    const float4 xv3 = xr[48 + kc];
#pragma unroll
    for (int u = 0; u < HH; ++u) {
      const float4 wv = ((const float4*)Wl)[u * 16 + kc];  // broadcast, reused 4x
      acc[0][u] += wv.x * xv0.x + wv.y * xv0.y + wv.z * xv0.z + wv.w * xv0.w;
      acc[1][u] += wv.x * xv1.x + wv.y * xv1.y + wv.z * xv1.z + wv.w * xv1.w;
      acc[2][u] += wv.x * xv2.x + wv.y * xv2.y + wv.z * xv2.z + wv.w * xv2.w;
      acc[3][u] += wv.x * xv3.x + wv.y * xv3.y + wv.z * xv3.z + wv.w * xv3.w;
    }
  }
  float4* op = (float4*)(u0 + row0 * HH);  // 4 rows = 32 float4 contiguous
#pragma unroll
  for (int r = 0; r < 4; ++r)
#pragma unroll
    for (int j = 0; j < 8; ++j)
      op[r * 8 + j] = make_float4(acc[r][4 * j], acc[r][4 * j + 1],
                                  acc[r][4 * j + 2], acc[r][4 * j + 3]);
}

// ---------------- recurrent kernel: 4 waves (one per layer), 16 ticks/barrier,
// fused per-row softmax epilogue (byte-identical to R16) ----------------
__global__ __launch_bounds__(256, 2) void rnn_kernel(
    const float* __restrict__ u0g_all, const float* __restrict__ h_state,
    const float* __restrict__ W_ih_rest, const float* __restrict__ W_hh,
    const float* __restrict__ b_ih, const float* __restrict__ b_hh,
    const float* __restrict__ fc_w, const float* __restrict__ fc_b,
    float* __restrict__ out) {
  __shared__ int hb[LL][2][KB][16];  // [layer][buf=n&1][i=tick-in-block][pair] f16x2
  __shared__ float h3f[2][KB][32];   // [buf][i][unit]: wave3's f32 hv for FC
  __shared__ float lrow[SS];         // full logit row (4KB), softmaxed at the end
  __shared__ float red[8];           // softmax cross-wave reduce

  const int tid  = threadIdx.x;
  const int wid  = tid >> 6;   // wave id == layer id
  const int lane = tid & 63;
  const int b    = blockIdx.x; // one batch element per block
  const int ks   = lane & 1;   // k-split half
  const int h    = lane >> 1;  // output unit 0..31

  // weights: f16-packed h-matrices only (x-part of layer 0 lives in u0)
  v2h wih[8], whh[8];
  {
    const float2* ph = (const float2*)(W_hh + (size_t)(wid * HH + h) * HH + ks * 16);
#pragma unroll
    for (int j = 0; j < 8; ++j) whh[j] = __builtin_amdgcn_cvt_pkrtz(ph[j].x, ph[j].y);
  }
  float bias = 0.f;  // layer 0 bias folded into u0
  if (wid > 0) {
    const float2* pi =
        (const float2*)(W_ih_rest + (size_t)((wid - 1) * HH + h) * HH + ks * 16);
#pragma unroll
    for (int j = 0; j < 8; ++j) wih[j] = __builtin_amdgcn_cvt_pkrtz(pi[j].x, pi[j].y);
    bias = b_ih[wid * HH + h] + b_hh[wid * HH + h];
  }
  const float fcwh = fc_w[h] * 0.5f;  // both ks lanes hold hv -> 64-lane sum is 2x
  const float fcb  = fc_b[0];

  // own h(-1) straight into registers (packed ks-half)
  v2h sv[8];
  {
    const float2* hs = (const float2*)(h_state + (size_t)(wid * BB + b) * HH);
#pragma unroll
    for (int j = 0; j < 8; ++j)
      sv[j] = __builtin_amdgcn_cvt_pkrtz(hs[ks * 8 + j].x, hs[ks * 8 + j].y);
  }

  const float* ug = u0g_all + (size_t)b * SS * HH;
  float* const hfin = out + (size_t)BB * SS;

  auto ld8 = [&](const int* p, v2h* v) __attribute__((always_inline)) {
    const uint4* q = (const uint4*)p;
    uint4 A = q[0], B = q[1];
    v[0] = bch(A.x); v[1] = bch(A.y); v[2] = bch(A.z); v[3] = bch(A.w);
    v[4] = bch(B.x); v[5] = bch(B.y); v[6] = bch(B.z); v[7] = bch(B.w);
  };
  // pack own hv with neighbor-unit hv (quad_perm [2,3,2,3]); word m valid at lane 4m
  auto packpair = [&](float hv) __attribute__((always_inline)) {
    return bcu(__builtin_amdgcn_cvt_pkrtz(hv, dpp_mov<0xEE>(hv)));
  };
  auto store_pk = [&](int l, int buf, int slot, unsigned pk) __attribute__((always_inline)) {
    if ((lane & 3) == 0) hb[l][buf][slot][lane >> 2] = (int)pk;
  };
  auto fcred = [&](float v) __attribute__((always_inline)) {
    v = dpp_add<0x111>(v);  // row_shr:1
    v = dpp_add<0x112>(v);  // row_shr:2
    v = dpp_add<0x114>(v);  // row_shr:4
    v = dpp_add<0x118>(v);  // row_shr:8
    v = dpp_add<0x142>(v);  // row_bcast:15
    v = dpp_add<0x143>(v);  // row_bcast:31
    return v;               // lane 63 holds the 64-lane sum
  };

  // Schedule: wave l computes tick block 16(n-l)..16(n-l)+15 at iteration n
  // (active for l <= n <= 63+l). Writes go to hb[l][n&1][i]; the consumer reads
  // the producer's same-range block (written at n-1) from buf (n-1)&1. FC
  // (wave 0) processes wave3's block from n-1 into lrow. All waves execute
  // exactly 68 barriers (n = 0..67).
  if (wid == 0) {
    float urA[KB], urB[KB];  // u0 prefetch, ping-pong by outer 2-unroll
#pragma unroll
    for (int i = 0; i < KB; ++i) urA[i] = ug[i * HH + h];  // block 0
    auto iter0 = [&](int n, int buf, float* urC, float* urN)
        __attribute__((always_inline)) {
      BAR();
      const bool fc_on = (n >= 4);   // n <= 67 by loop bound
      const bool cw    = (n <= 63);
      float a[KB];
      if (fc_on) {
#pragma unroll
        for (int i = 0; i < KB; ++i) a[i] = h3f[buf ^ 1][i][h];
      }
      if (cw) {
        const int tb = KB * (n + 1);  // prefetch u0 for next block (off-chain)
#pragma unroll
        for (int i = 0; i < KB; ++i) {
          int t = tb + i; t = t < SS ? t : SS - 1;
          urN[i] = ug[t * HH + h];    // survives BAR (lgkm-only)
        }
        float hvL = 0.f;
#pragma unroll
        for (int i = 0; i < KB; ++i) {
          float acc = dot16p(whh, sv);
          acc = dpp_add<0xB1>(acc) + urC[i];  // u0 holds x-part + full bias0
          const float hv = tanh_fast(acc);
          const unsigned pk = packpair(hv);
          store_pk(0, buf, i, pk);
          ld8(&hb[0][buf][i][ks * 8], sv);    // own carry (in-order DS RAW)
          if (i == KB - 1) hvL = hv;
        }
        if (n == 63 && ks == 0) hfin[(0 * BB + b) * HH + h] = hvL;
      }
      if (fc_on) {  // FC for wave3's block from iter n-1: t = 16(n-4)+i
        const int tf0 = KB * (n - 4);
#pragma unroll
        for (int i = 0; i < KB; ++i) {
          float v = fcred(a[i] * fcwh);
          if (lane == 63) lrow[tf0 + i] = v + fcb;
        }
      }
    };
    for (int n0 = 0; n0 < 68; n0 += 2) {
      iter0(n0, 0, urA, urB);
      iter0(n0 + 1, 1, urB, urA);
    }
  } else {
    v2h viA[4][8], viB[4][8];  // input groups of 4 ticks, double-banked
    auto ldgrp = [&](int buf, int g, v2h (*vv)[8]) __attribute__((always_inline)) {
#pragma unroll
      for (int q = 0; q < 4; ++q)
        ld8(&hb[wid - 1][buf ^ 1][g * 4 + q][ks * 8], vv[q]);
    };
    auto dogrp = [&](int n, int buf, int g, v2h (*vc)[8], float& hvL)
        __attribute__((always_inline)) {
#pragma unroll
      for (int q = 0; q < 4; ++q) {
        const int i = g * 4 + q;
        float accA = dot16p(wih, vc[q]);      // independent: overlaps carry wait
        float acc = accA + dot16p(whh, sv);
        acc = dpp_add<0xB1>(acc) + bias;
        const float hv = tanh_fast(acc);
        const unsigned pk = packpair(hv);
        store_pk(wid, buf, i, pk);
        if (wid == 3 && ks == 0) h3f[buf][i][h] = hv;  // f32 handoff to FC
        ld8(&hb[wid][buf][i][ks * 8], sv);             // own carry
        if (i == KB - 1) hvL = hv;
      }
    };
    auto iterl = [&](int n, int buf) __attribute__((always_inline)) {
      BAR();
      const bool cw = (n >= wid && n <= 63 + wid);
      if (cw) {
        float hvL = 0.f;
        ldgrp(buf, 0, viA);
        ldgrp(buf, 1, viB);          // prefetch group 1
        dogrp(n, buf, 0, viA, hvL);
        ldgrp(buf, 2, viA);          // prefetch group 2 (viA free)
        dogrp(n, buf, 1, viB, hvL);
        ldgrp(buf, 3, viB);          // prefetch group 3 (viB free)
        dogrp(n, buf, 2, viA, hvL);
        dogrp(n, buf, 3, viB, hvL);
        if (n == 63 + wid && ks == 0) hfin[(wid * BB + b) * HH + h] = hvL;
      }
    };
    for (int n0 = 0; n0 < 68; n0 += 2) {
      iterl(n0, 0);
      iterl(n0 + 1, 1);
    }
  }

  // ---- fused softmax over lrow (exact replica of the old softmax_kernel) ----
  __syncthreads();  // all lrow writes (wave 0, LDS) visible to all waves
  {
    float4 v = ((const float4*)lrow)[tid];  // 256 threads x 4 = 1024 logits
    float m = fmaxf(fmaxf(v.x, v.y), fmaxf(v.z, v.w));
#pragma unroll
    for (int d = 32; d >= 1; d >>= 1) m = fmaxf(m, __shfl_xor(m, d));
    if ((tid & 63) == 0) red[tid >> 6] = m;
    __syncthreads();
    m = fmaxf(fmaxf(red[0], red[1]), fmaxf(red[2], red[3]));
    const float e0 = __expf(v.x - m), e1 = __expf(v.y - m);
    const float e2 = __expf(v.z - m), e3 = __expf(v.w - m);
    float s = (e0 + e1) + (e2 + e3);
#pragma unroll
    for (int d = 32; d >= 1; d >>= 1) s += __shfl_xor(s, d);
    if ((tid & 63) == 0) red[4 + (tid >> 6)] = s;
    __syncthreads();
    s = (red[4] + red[5]) + (red[6] + red[7]);
    const float inv = 1.0f / s;
    float4 o;
    o.x = e0 * inv; o.y = e1 * inv; o.z = e2 * inv; o.w = e3 * inv;
    ((float4*)(out + (size_t)b * SS))[tid] = o;
  }
}

extern "C" void kernel_launch(void* const* d_in, const int* in_sizes, int n_in,
                              void* d_out, int out_size, void* d_ws, size_t ws_size,
                              hipStream_t stream) {
  const float* x         = (const float*)d_in[0];
  const float* h_state   = (const float*)d_in[1];
  const float* W_ih0     = (const float*)d_in[2];
  const float* W_ih_rest = (const float*)d_in[3];
  const float* W_hh      = (const float*)d_in[4];
  const float* b_ih      = (const float*)d_in[5];
  const float* b_hh      = (const float*)d_in[6];
  const float* fc_w      = (const float*)d_in[7];
  const float* fc_b      = (const float*)d_in[8];
  float* out = (float*)d_out;
  float* u0  = (float*)d_ws;  // [B,S,32] fp32 = 67 MB scratch

  hipLaunchKernelGGL(u0_kernel, dim3(512), dim3(256), 0, stream,
                     x, W_ih0, b_ih, b_hh, u0);
  hipLaunchKernelGGL(rnn_kernel, dim3(BB), dim3(256), 0, stream,
                     u0, h_state, W_ih_rest, W_hh, b_ih, b_hh, fc_w, fc_b, out);
}

// Round 10
// 433.358 us; speedup vs baseline: 1.0640x; 1.0640x over previous
//
#include <hip/hip_runtime.h>

// RadarRnn1: 4-layer tanh RNN (B=512,S=1024,IN=64,H=32) + per-step FC + softmax over S.
// R18: R17's 4-row u0 regressed (+35us): 1KB lane stride = 64 lines/load, 64KB
// wave working-set > L1, + occupancy drop from launch_bounds(256,1). Same
// DS-amortization idea, locality-preserving: 2 rows/thread INTERLEAVED
// (row1 = row0 + 256; 1024 blocks x 256 threads):
//   - per-lane x stride stays 256B (proven R16 pattern); 2 streams x 16KB
//     window = 32KB = exactly L1; lines fully consumed in the unroll-4 window.
//   - each broadcast W ds_read_b128 feeds 2 accumulators: DS instrs/row 8 -> 4
//     (~68 -> ~34us chip-wide DS serialization).
//   - acc[2][32]=64 VGPR (~90 total, 5 waves/SIMD), default launch bounds.
//   - per-row FP32 expression order identical to R16 -> bit-identical u0.
// rnn_kernel: byte-identical to R16 (221us proven) for clean attribution.

#define BB 512
#define SS 1024
#define INF 64
#define HH 32
#define LL 4
#define KB 16  // ticks per barrier iteration

typedef __fp16 v2h __attribute__((ext_vector_type(2)));

__device__ __forceinline__ v2h bch(unsigned u) { return __builtin_bit_cast(v2h, u); }
__device__ __forceinline__ unsigned bcu(v2h h) { return __builtin_bit_cast(unsigned, h); }

template <int CTRL>
__device__ __forceinline__ float dpp_add(float v) {
  int y = __builtin_amdgcn_update_dpp(0, __float_as_int(v), CTRL, 0xF, 0xF, true);
  return v + __int_as_float(y);
}
template <int CTRL>
__device__ __forceinline__ float dpp_mov(float v) {
  int y = __builtin_amdgcn_update_dpp(0, __float_as_int(v), CTRL, 0xF, 0xF, true);
  return __int_as_float(y);
}

// tanh(a) = 1 - 2/(e^{2a}+1); e^{2a} = 2^(a * 2/ln2). v_exp + v_rcp + fma.
__device__ __forceinline__ float tanh_fast(float a) {
  const float e = __builtin_amdgcn_exp2f(a * 2.885390081777927f);
  const float r = __builtin_amdgcn_rcpf(e + 1.0f);
  return __builtin_fmaf(-2.0f, r, 1.0f);
}

// 16-half dot (ks-half): 8 fdot2 in 2 chains of depth 4.
__device__ __forceinline__ float dot16p(const v2h* w, const v2h* v) {
  float a = 0.f, c = 0.f;
#pragma unroll
  for (int j = 0; j < 4; ++j) {
    a = __builtin_amdgcn_fdot2(w[2 * j + 0], v[2 * j + 0], a, false);
    c = __builtin_amdgcn_fdot2(w[2 * j + 1], v[2 * j + 1], c, false);
  }
  return a + c;
}

// lgkmcnt-only barrier: drains LDS ops (cross-wave handoff) but leaves global
// loads/stores in flight (u0 prefetch, hfin stores).
#define BAR() asm volatile("s_waitcnt lgkmcnt(0)\n\ts_barrier" ::: "memory")

// ---------------- u0 = x @ W_ih0^T + (b_ih0 + b_hh0) ----------------
// R18: 2 interleaved rows/thread; each broadcast W read feeds both rows.
__global__ __launch_bounds__(256) void u0_kernel(
    const float* __restrict__ x, const float* __restrict__ W_ih0,
    const float* __restrict__ b_ih, const float* __restrict__ b_hh,
    float* __restrict__ u0) {
  __shared__ float Wl[HH * INF];  // [u][k]
  __shared__ float bl[HH];
  const int tid = threadIdx.x;
  {
    const float4* src = (const float4*)W_ih0;
    float4* dst = (float4*)Wl;
    dst[tid] = src[tid];
    dst[tid + 256] = src[tid + 256];
    if (tid < HH) bl[tid] = b_ih[tid] + b_hh[tid];
  }
  __syncthreads();

  // 1024 blocks x 256 threads x 2 rows; row1 = row0 + 256 keeps the proven
  // 256B lane stride on x (L1-friendly) for both streams.
  const size_t row0 = (size_t)blockIdx.x * 512 + tid;
  const size_t row1 = row0 + 256;
  const float4* xr0 = (const float4*)(x + row0 * INF);
  const float4* xr1 = (const float4*)(x + row1 * INF);
  float acc0[HH], acc1[HH];
#pragma unroll
  for (int u = 0; u < HH; ++u) { acc0[u] = bl[u]; acc1[u] = bl[u]; }
#pragma unroll 4
  for (int kc = 0; kc < 16; ++kc) {
    const float4 xa = xr0[kc];
    const float4 xb = xr1[kc];
#pragma unroll
    for (int u = 0; u < HH; ++u) {
      const float4 wv = ((const float4*)Wl)[u * 16 + kc];  // broadcast, reused 2x
      acc0[u] += wv.x * xa.x + wv.y * xa.y + wv.z * xa.z + wv.w * xa.w;
      acc1[u] += wv.x * xb.x + wv.y * xb.y + wv.z * xb.z + wv.w * xb.w;
    }
  }
  float4* op0 = (float4*)(u0 + row0 * HH);
  float4* op1 = (float4*)(u0 + row1 * HH);
#pragma unroll
  for (int j = 0; j < 8; ++j) {
    op0[j] = make_float4(acc0[4 * j], acc0[4 * j + 1], acc0[4 * j + 2], acc0[4 * j + 3]);
    op1[j] = make_float4(acc1[4 * j], acc1[4 * j + 1], acc1[4 * j + 2], acc1[4 * j + 3]);
  }
}

// ---------------- recurrent kernel: 4 waves (one per layer), 16 ticks/barrier,
// fused per-row softmax epilogue (byte-identical to R16) ----------------
__global__ __launch_bounds__(256, 2) void rnn_kernel(
    const float* __restrict__ u0g_all, const float* __restrict__ h_state,
    const float* __restrict__ W_ih_rest, const float* __restrict__ W_hh,
    const float* __restrict__ b_ih, const float* __restrict__ b_hh,
    const float* __restrict__ fc_w, const float* __restrict__ fc_b,
    float* __restrict__ out) {
  __shared__ int hb[LL][2][KB][16];  // [layer][buf=n&1][i=tick-in-block][pair] f16x2
  __shared__ float h3f[2][KB][32];   // [buf][i][unit]: wave3's f32 hv for FC
  __shared__ float lrow[SS];         // full logit row (4KB), softmaxed at the end
  __shared__ float red[8];           // softmax cross-wave reduce

  const int tid  = threadIdx.x;
  const int wid  = tid >> 6;   // wave id == layer id
  const int lane = tid & 63;
  const int b    = blockIdx.x; // one batch element per block
  const int ks   = lane & 1;   // k-split half
  const int h    = lane >> 1;  // output unit 0..31

  // weights: f16-packed h-matrices only (x-part of layer 0 lives in u0)
  v2h wih[8], whh[8];
  {
    const float2* ph = (const float2*)(W_hh + (size_t)(wid * HH + h) * HH + ks * 16);
#pragma unroll
    for (int j = 0; j < 8; ++j) whh[j] = __builtin_amdgcn_cvt_pkrtz(ph[j].x, ph[j].y);
  }
  float bias = 0.f;  // layer 0 bias folded into u0
  if (wid > 0) {
    const float2* pi =
        (const float2*)(W_ih_rest + (size_t)((wid - 1) * HH + h) * HH + ks * 16);
#pragma unroll
    for (int j = 0; j < 8; ++j) wih[j] = __builtin_amdgcn_cvt_pkrtz(pi[j].x, pi[j].y);
    bias = b_ih[wid * HH + h] + b_hh[wid * HH + h];
  }
  const float fcwh = fc_w[h] * 0.5f;  // both ks lanes hold hv -> 64-lane sum is 2x
  const float fcb  = fc_b[0];

  // own h(-1) straight into registers (packed ks-half)
  v2h sv[8];
  {
    const float2* hs = (const float2*)(h_state + (size_t)(wid * BB + b) * HH);
#pragma unroll
    for (int j = 0; j < 8; ++j)
      sv[j] = __builtin_amdgcn_cvt_pkrtz(hs[ks * 8 + j].x, hs[ks * 8 + j].y);
  }

  const float* ug = u0g_all + (size_t)b * SS * HH;
  float* const hfin = out + (size_t)BB * SS;

  auto ld8 = [&](const int* p, v2h* v) __attribute__((always_inline)) {
    const uint4* q = (const uint4*)p;
    uint4 A = q[0], B = q[1];
    v[0] = bch(A.x); v[1] = bch(A.y); v[2] = bch(A.z); v[3] = bch(A.w);
    v[4] = bch(B.x); v[5] = bch(B.y); v[6] = bch(B.z); v[7] = bch(B.w);
  };
  // pack own hv with neighbor-unit hv (quad_perm [2,3,2,3]); word m valid at lane 4m
  auto packpair = [&](float hv) __attribute__((always_inline)) {
    return bcu(__builtin_amdgcn_cvt_pkrtz(hv, dpp_mov<0xEE>(hv)));
  };
  auto store_pk = [&](int l, int buf, int slot, unsigned pk) __attribute__((always_inline)) {
    if ((lane & 3) == 0) hb[l][buf][slot][lane >> 2] = (int)pk;
  };
  auto fcred = [&](float v) __attribute__((always_inline)) {
    v = dpp_add<0x111>(v);  // row_shr:1
    v = dpp_add<0x112>(v);  // row_shr:2
    v = dpp_add<0x114>(v);  // row_shr:4
    v = dpp_add<0x118>(v);  // row_shr:8
    v = dpp_add<0x142>(v);  // row_bcast:15
    v = dpp_add<0x143>(v);  // row_bcast:31
    return v;               // lane 63 holds the 64-lane sum
  };

  // Schedule: wave l computes tick block 16(n-l)..16(n-l)+15 at iteration n
  // (active for l <= n <= 63+l). Writes go to hb[l][n&1][i]; the consumer reads
  // the producer's same-range block (written at n-1) from buf (n-1)&1. FC
  // (wave 0) processes wave3's block from n-1 into lrow. All waves execute
  // exactly 68 barriers (n = 0..67).
  if (wid == 0) {
    float urA[KB], urB[KB];  // u0 prefetch, ping-pong by outer 2-unroll
#pragma unroll
    for (int i = 0; i < KB; ++i) urA[i] = ug[i * HH + h];  // block 0
    auto iter0 = [&](int n, int buf, float* urC, float* urN)
        __attribute__((always_inline)) {
      BAR();
      const bool fc_on = (n >= 4);   // n <= 67 by loop bound
      const bool cw    = (n <= 63);
      float a[KB];
      if (fc_on) {
#pragma unroll
        for (int i = 0; i < KB; ++i) a[i] = h3f[buf ^ 1][i][h];
      }
      if (cw) {
        const int tb = KB * (n + 1);  // prefetch u0 for next block (off-chain)
#pragma unroll
        for (int i = 0; i < KB; ++i) {
          int t = tb + i; t = t < SS ? t : SS - 1;
          urN[i] = ug[t * HH + h];    // survives BAR (lgkm-only)
        }
        float hvL = 0.f;
#pragma unroll
        for (int i = 0; i < KB; ++i) {
          float acc = dot16p(whh, sv);
          acc = dpp_add<0xB1>(acc) + urC[i];  // u0 holds x-part + full bias0
          const float hv = tanh_fast(acc);
          const unsigned pk = packpair(hv);
          store_pk(0, buf, i, pk);
          ld8(&hb[0][buf][i][ks * 8], sv);    // own carry (in-order DS RAW)
          if (i == KB - 1) hvL = hv;
        }
        if (n == 63 && ks == 0) hfin[(0 * BB + b) * HH + h] = hvL;
      }
      if (fc_on) {  // FC for wave3's block from iter n-1: t = 16(n-4)+i
        const int tf0 = KB * (n - 4);
#pragma unroll
        for (int i = 0; i < KB; ++i) {
          float v = fcred(a[i] * fcwh);
          if (lane == 63) lrow[tf0 + i] = v + fcb;
        }
      }
    };
    for (int n0 = 0; n0 < 68; n0 += 2) {
      iter0(n0, 0, urA, urB);
      iter0(n0 + 1, 1, urB, urA);
    }
  } else {
    v2h viA[4][8], viB[4][8];  // input groups of 4 ticks, double-banked
    auto ldgrp = [&](int buf, int g, v2h (*vv)[8]) __attribute__((always_inline)) {
#pragma unroll
      for (int q = 0; q < 4; ++q)
        ld8(&hb[wid - 1][buf ^ 1][g * 4 + q][ks * 8], vv[q]);
    };
    auto dogrp = [&](int n, int buf, int g, v2h (*vc)[8], float& hvL)
        __attribute__((always_inline)) {
#pragma unroll
      for (int q = 0; q < 4; ++q) {
        const int i = g * 4 + q;
        float accA = dot16p(wih, vc[q]);      // independent: overlaps carry wait
        float acc = accA + dot16p(whh, sv);
        acc = dpp_add<0xB1>(acc) + bias;
        const float hv = tanh_fast(acc);
        const unsigned pk = packpair(hv);
        store_pk(wid, buf, i, pk);
        if (wid == 3 && ks == 0) h3f[buf][i][h] = hv;  // f32 handoff to FC
        ld8(&hb[wid][buf][i][ks * 8], sv);             // own carry
        if (i == KB - 1) hvL = hv;
      }
    };
    auto iterl = [&](int n, int buf) __attribute__((always_inline)) {
      BAR();
      const bool cw = (n >= wid && n <= 63 + wid);
      if (cw) {
        float hvL = 0.f;
        ldgrp(buf, 0, viA);
        ldgrp(buf, 1, viB);          // prefetch group 1
        dogrp(n, buf, 0, viA, hvL);
        ldgrp(buf, 2, viA);          // prefetch group 2 (viA free)
        dogrp(n, buf, 1, viB, hvL);
        ldgrp(buf, 3, viB);          // prefetch group 3 (viB free)
        dogrp(n, buf, 2, viA, hvL);
        dogrp(n, buf, 3, viB, hvL);
        if (n == 63 + wid && ks == 0) hfin[(wid * BB + b) * HH + h] = hvL;
      }
    };
    for (int n0 = 0; n0 < 68; n0 += 2) {
      iterl(n0, 0);
      iterl(n0 + 1, 1);
    }
  }

  // ---- fused softmax over lrow (exact replica of the old softmax_kernel) ----
  __syncthreads();  // all lrow writes (wave 0, LDS) visible to all waves
  {
    float4 v = ((const float4*)lrow)[tid];  // 256 threads x 4 = 1024 logits
    float m = fmaxf(fmaxf(v.x, v.y), fmaxf(v.z, v.w));
#pragma unroll
    for (int d = 32; d >= 1; d >>= 1) m = fmaxf(m, __shfl_xor(m, d));
    if ((tid & 63) == 0) red[tid >> 6] = m;
    __syncthreads();
    m = fmaxf(fmaxf(red[0], red[1]), fmaxf(red[2], red[3]));
    const float e0 = __expf(v.x - m), e1 = __expf(v.y - m);
    const float e2 = __expf(v.z - m), e3 = __expf(v.w - m);
    float s = (e0 + e1) + (e2 + e3);
#pragma unroll
    for (int d = 32; d >= 1; d >>= 1) s += __shfl_xor(s, d);
    if ((tid & 63) == 0) red[4 + (tid >> 6)] = s;
    __syncthreads();
    s = (red[4] + red[5]) + (red[6] + red[7]);
    const float inv = 1.0f / s;
    float4 o;
    o.x = e0 * inv; o.y = e1 * inv; o.z = e2 * inv; o.w = e3 * inv;
    ((float4*)(out + (size_t)b * SS))[tid] = o;
  }
}

extern "C" void kernel_launch(void* const* d_in, const int* in_sizes, int n_in,
                              void* d_out, int out_size, void* d_ws, size_t ws_size,
                              hipStream_t stream) {
  const float* x         = (const float*)d_in[0];
  const float* h_state   = (const float*)d_in[1];
  const float* W_ih0     = (const float*)d_in[2];
  const float* W_ih_rest = (const float*)d_in[3];
  const float* W_hh      = (const float*)d_in[4];
  const float* b_ih      = (const float*)d_in[5];
  const float* b_hh      = (const float*)d_in[6];
  const float* fc_w      = (const float*)d_in[7];
  const float* fc_b      = (const float*)d_in[8];
  float* out = (float*)d_out;
  float* u0  = (float*)d_ws;  // [B,S,32] fp32 = 67 MB scratch

  hipLaunchKernelGGL(u0_kernel, dim3(1024), dim3(256), 0, stream,
                     x, W_ih0, b_ih, b_hh, u0);
  hipLaunchKernelGGL(rnn_kernel, dim3(BB), dim3(256), 0, stream,
                     u0, h_state, W_ih_rest, W_hh, b_ih, b_hh, fc_w, fc_b, out);
}

// Round 11
// 411.136 us; speedup vs baseline: 1.1215x; 1.0541x over previous
//
#include <hip/hip_runtime.h>

// RadarRnn1: 4-layer tanh RNN (B=512,S=1024,IN=64,H=32) + per-step FC + softmax over S.
// R19: u0 DS-amortization falsified twice (R17 +35us, R18 +9us) - u0's actual
// bottleneck is invisible (never top-5). Residue (~210us) is u0 + launch +
// fixed overhead. Fix: ELIMINATE u0 as a kernel. The rnn block is 79% idle
// (Occ 21%, 4 waves); fuse u0 in as 4 PRODUCER waves (block = 512 threads):
//   - wave 4+p at iteration n computes u0 ticks 16(n+1)+4p..+3 for this batch:
//     per lane (h,ks) a 32-term f32 half-dot (8 coalesced float4 x-loads vs
//     f32 W_ih0 half-row in regs), dpp cross-ks combine, +bias -> LDS ring
//     lu0[2][16][32] (block 0 done pre-loop). Same f32 4-term group order as
//     the old u0; only the half-combine order differs (absmax robustness to
//     summation order proven by R11/R13/R14: all 0.00390625).
//   - wave 0 reads ur[i] from lu0[n&1] (16 conflict-free ds_read_b32 batched
//     post-BAR) instead of global prefetch.
//   - ring parity: producers write buf (n+1)&1, wave0 reads buf n&1; reads
//     drain at BAR lgkmcnt(0) one window before rewrite (proven discipline).
//   - deletes: u0 kernel + launch + 67MB write + 67MB read. x (134MB) read
//     once by producer waves with huge slack.
// Softmax epilogue: compute guarded tid<256 (wave-uniform), syncs outside
// guards -> bit-identical. Waves 1-3 pipeline code byte-identical to R16.

#define BB 512
#define SS 1024
#define INF 64
#define HH 32
#define LL 4
#define KB 16  // ticks per barrier iteration

typedef __fp16 v2h __attribute__((ext_vector_type(2)));

__device__ __forceinline__ v2h bch(unsigned u) { return __builtin_bit_cast(v2h, u); }
__device__ __forceinline__ unsigned bcu(v2h h) { return __builtin_bit_cast(unsigned, h); }

template <int CTRL>
__device__ __forceinline__ float dpp_add(float v) {
  int y = __builtin_amdgcn_update_dpp(0, __float_as_int(v), CTRL, 0xF, 0xF, true);
  return v + __int_as_float(y);
}
template <int CTRL>
__device__ __forceinline__ float dpp_mov(float v) {
  int y = __builtin_amdgcn_update_dpp(0, __float_as_int(v), CTRL, 0xF, 0xF, true);
  return __int_as_float(y);
}

// tanh(a) = 1 - 2/(e^{2a}+1); e^{2a} = 2^(a * 2/ln2). v_exp + v_rcp + fma.
__device__ __forceinline__ float tanh_fast(float a) {
  const float e = __builtin_amdgcn_exp2f(a * 2.885390081777927f);
  const float r = __builtin_amdgcn_rcpf(e + 1.0f);
  return __builtin_fmaf(-2.0f, r, 1.0f);
}

// 16-half dot (ks-half): 8 fdot2 in 2 chains of depth 4.
__device__ __forceinline__ float dot16p(const v2h* w, const v2h* v) {
  float a = 0.f, c = 0.f;
#pragma unroll
  for (int j = 0; j < 4; ++j) {
    a = __builtin_amdgcn_fdot2(w[2 * j + 0], v[2 * j + 0], a, false);
    c = __builtin_amdgcn_fdot2(w[2 * j + 1], v[2 * j + 1], c, false);
  }
  return a + c;
}

// lgkmcnt-only barrier: drains LDS ops (cross-wave handoff) but leaves global
// loads/stores in flight (x loads, hfin stores).
#define BAR() asm volatile("s_waitcnt lgkmcnt(0)\n\ts_barrier" ::: "memory")

// ---------------- fused kernel: 4 pipeline waves + 4 u0-producer waves ----------------
__global__ __launch_bounds__(512, 4) void rnn_kernel(
    const float* __restrict__ x, const float* __restrict__ h_state,
    const float* __restrict__ W_ih0, const float* __restrict__ W_ih_rest,
    const float* __restrict__ W_hh, const float* __restrict__ b_ih,
    const float* __restrict__ b_hh, const float* __restrict__ fc_w,
    const float* __restrict__ fc_b, float* __restrict__ out) {
  __shared__ int hb[LL][2][KB][16];  // [layer][buf=n&1][i][pair] f16x2
  __shared__ float h3f[2][KB][32];   // [buf][i][unit]: wave3's f32 hv for FC
  __shared__ float lu0[2][KB][32];   // [buf][i][unit]: u0 ring from producers
  __shared__ float lrow[SS];         // full logit row (4KB), softmaxed at the end
  __shared__ float red[8];           // softmax cross-wave reduce

  const int tid  = threadIdx.x;
  const int wid  = tid >> 6;   // 0..3 pipeline (layer), 4..7 u0 producers
  const int lane = tid & 63;
  const int b    = blockIdx.x; // one batch element per block
  const int ks   = lane & 1;   // k-split half
  const int h    = lane >> 1;  // output unit 0..31

  // pipeline-wave weights: f16-packed h-matrices (x-part of layer 0 = u0)
  v2h wih[8], whh[8];
  float bias = 0.f;
  if (wid < LL) {
    const float2* ph = (const float2*)(W_hh + (size_t)(wid * HH + h) * HH + ks * 16);
#pragma unroll
    for (int j = 0; j < 8; ++j) whh[j] = __builtin_amdgcn_cvt_pkrtz(ph[j].x, ph[j].y);
    if (wid > 0) {
      const float2* pi =
          (const float2*)(W_ih_rest + (size_t)((wid - 1) * HH + h) * HH + ks * 16);
#pragma unroll
      for (int j = 0; j < 8; ++j) wih[j] = __builtin_amdgcn_cvt_pkrtz(pi[j].x, pi[j].y);
      bias = b_ih[wid * HH + h] + b_hh[wid * HH + h];
    }
  }
  // producer-wave weights: f32 W_ih0 half-row (preserves u0's f32 numerics)
  float4 wv4[8];
  float bias0 = 0.f;
  if (wid >= LL) {
    const float4* wr = (const float4*)(W_ih0 + (size_t)h * INF + ks * 32);
#pragma unroll
    for (int j = 0; j < 8; ++j) wv4[j] = wr[j];
    bias0 = b_ih[h] + b_hh[h];
  }
  const float fcwh = fc_w[h] * 0.5f;  // both ks lanes hold hv -> 64-lane sum is 2x
  const float fcb  = fc_b[0];

  // own h(-1) straight into registers (packed ks-half) - pipeline waves only
  v2h sv[8];
  if (wid < LL) {
    const float2* hs = (const float2*)(h_state + (size_t)(wid * BB + b) * HH);
#pragma unroll
    for (int j = 0; j < 8; ++j)
      sv[j] = __builtin_amdgcn_cvt_pkrtz(hs[ks * 8 + j].x, hs[ks * 8 + j].y);
  }

  float* const hfin = out + (size_t)BB * SS;

  auto ld8 = [&](const int* p, v2h* v) __attribute__((always_inline)) {
    const uint4* q = (const uint4*)p;
    uint4 A = q[0], B = q[1];
    v[0] = bch(A.x); v[1] = bch(A.y); v[2] = bch(A.z); v[3] = bch(A.w);
    v[4] = bch(B.x); v[5] = bch(B.y); v[6] = bch(B.z); v[7] = bch(B.w);
  };
  auto packpair = [&](float hv) __attribute__((always_inline)) {
    return bcu(__builtin_amdgcn_cvt_pkrtz(hv, dpp_mov<0xEE>(hv)));
  };
  auto store_pk = [&](int l, int buf, int slot, unsigned pk) __attribute__((always_inline)) {
    if ((lane & 3) == 0) hb[l][buf][slot][lane >> 2] = (int)pk;
  };
  auto fcred = [&](float v) __attribute__((always_inline)) {
    v = dpp_add<0x111>(v);  // row_shr:1
    v = dpp_add<0x112>(v);  // row_shr:2
    v = dpp_add<0x114>(v);  // row_shr:4
    v = dpp_add<0x118>(v);  // row_shr:8
    v = dpp_add<0x142>(v);  // row_bcast:15
    v = dpp_add<0x143>(v);  // row_bcast:31
    return v;               // lane 63 holds the 64-lane sum
  };

  // Schedule (68 barrier-iterations, all 8 waves in lock-step):
  //  wave l (0..3): tick block 16(n-l)..+15 at iteration n (active l<=n<=63+l),
  //    identical to R16. wave 0's u0 inputs come from lu0[n&1].
  //  wave 4+p: during iteration n (n<=62) computes u0 for ticks
  //    16(n+1)+4p..+3 into lu0[(n+1)&1]; block 0 is produced PRE-loop
  //    (published by BAR(0)). Ring safety: wave0's reads of buf n&1 drain at
  //    its lgkmcnt(0) before BAR(n+1); producers rewrite that buf after
  //    BAR(n+1).
  if (wid == 0) {
    for (int n = 0; n < 68; ++n) {
      BAR();
      const int buf = n & 1;
      const bool fc_on = (n >= 4);
      const bool cw    = (n <= 63);
      float a[KB];
      if (fc_on) {
#pragma unroll
        for (int i = 0; i < KB; ++i) a[i] = h3f[buf ^ 1][i][h];
      }
      if (cw) {
        float ur[KB];
#pragma unroll
        for (int i = 0; i < KB; ++i) ur[i] = lu0[buf][i][h];  // conflict-free b32
        float hvL = 0.f;
#pragma unroll
        for (int i = 0; i < KB; ++i) {
          float acc = dot16p(whh, sv);
          acc = dpp_add<0xB1>(acc) + ur[i];  // u0 holds x-part + full bias0
          const float hv = tanh_fast(acc);
          const unsigned pk = packpair(hv);
          store_pk(0, buf, i, pk);
          ld8(&hb[0][buf][i][ks * 8], sv);   // own carry (in-order DS RAW)
          if (i == KB - 1) hvL = hv;
        }
        if (n == 63 && ks == 0) hfin[(0 * BB + b) * HH + h] = hvL;
      }
      if (fc_on) {  // FC for wave3's block from iter n-1: t = 16(n-4)+i
        const int tf0 = KB * (n - 4);
#pragma unroll
        for (int i = 0; i < KB; ++i) {
          float v = fcred(a[i] * fcwh);
          if (lane == 63) lrow[tf0 + i] = v + fcb;
        }
      }
    }
  } else if (wid < LL) {
    v2h viA[4][8], viB[4][8];  // input groups of 4 ticks, double-banked
    auto ldgrp = [&](int buf, int g, v2h (*vv)[8]) __attribute__((always_inline)) {
#pragma unroll
      for (int q = 0; q < 4; ++q)
        ld8(&hb[wid - 1][buf ^ 1][g * 4 + q][ks * 8], vv[q]);
    };
    auto dogrp = [&](int n, int buf, int g, v2h (*vc)[8], float& hvL)
        __attribute__((always_inline)) {
#pragma unroll
      for (int q = 0; q < 4; ++q) {
        const int i = g * 4 + q;
        float accA = dot16p(wih, vc[q]);      // independent: overlaps carry wait
        float acc = accA + dot16p(whh, sv);
        acc = dpp_add<0xB1>(acc) + bias;
        const float hv = tanh_fast(acc);
        const unsigned pk = packpair(hv);
        store_pk(wid, buf, i, pk);
        if (wid == 3 && ks == 0) h3f[buf][i][h] = hv;  // f32 handoff to FC
        ld8(&hb[wid][buf][i][ks * 8], sv);             // own carry
        if (i == KB - 1) hvL = hv;
      }
    };
    auto iterl = [&](int n, int buf) __attribute__((always_inline)) {
      BAR();
      const bool cw = (n >= wid && n <= 63 + wid);
      if (cw) {
        float hvL = 0.f;
        ldgrp(buf, 0, viA);
        ldgrp(buf, 1, viB);          // prefetch group 1
        dogrp(n, buf, 0, viA, hvL);
        ldgrp(buf, 2, viA);          // prefetch group 2 (viA free)
        dogrp(n, buf, 1, viB, hvL);
        ldgrp(buf, 3, viB);          // prefetch group 3 (viB free)
        dogrp(n, buf, 2, viA, hvL);
        dogrp(n, buf, 3, viB, hvL);
        if (n == 63 + wid && ks == 0) hfin[(wid * BB + b) * HH + h] = hvL;
      }
    };
    for (int n0 = 0; n0 < 68; n0 += 2) {
      iterl(n0, 0);
      iterl(n0 + 1, 1);
    }
  } else {
    // u0 producers: wave 4+p covers tick offsets 4p..4p+3 of each block.
    const int p = wid - LL;
    const float* xb = x + (size_t)b * SS * INF;
    auto produce = [&](int blk) __attribute__((always_inline)) {
      const int buf = blk & 1;
      const int T = KB * blk + 4 * p;
#pragma unroll
      for (int q = 0; q < 4; ++q) {
        const float4* x4 = (const float4*)(xb + (size_t)(T + q) * INF + ks * 32);
        float acc = 0.f;
#pragma unroll
        for (int j = 0; j < 8; ++j) {
          const float4 xv = x4[j];
          acc += wv4[j].x * xv.x + wv4[j].y * xv.y + wv4[j].z * xv.z + wv4[j].w * xv.w;
        }
        const float tot = dpp_add<0xB1>(acc) + bias0;  // cross-ks combine
        if (ks == 0) lu0[buf][4 * p + q][h] = tot;     // 32 consec addrs, no conflict
      }
    };
    produce(0);  // block 0 pre-loop; published by BAR(0)
    for (int n = 0; n < 68; ++n) {
      BAR();
      if (n <= 62) produce(n + 1);
    }
  }

  // ---- fused softmax over lrow (bit-identical reduction, waves 0-3 only) ----
  __syncthreads();  // all lrow writes visible to all waves
  float4 v; float m; float e0, e1, e2, e3; float s;
  if (tid < 256) {  // wave-uniform guard
    v = ((const float4*)lrow)[tid];  // 256 threads x 4 = 1024 logits
    m = fmaxf(fmaxf(v.x, v.y), fmaxf(v.z, v.w));
#pragma unroll
    for (int d = 32; d >= 1; d >>= 1) m = fmaxf(m, __shfl_xor(m, d));
    if ((tid & 63) == 0) red[tid >> 6] = m;
  }
  __syncthreads();
  if (tid < 256) {
    m = fmaxf(fmaxf(red[0], red[1]), fmaxf(red[2], red[3]));
    e0 = __expf(v.x - m); e1 = __expf(v.y - m);
    e2 = __expf(v.z - m); e3 = __expf(v.w - m);
    s = (e0 + e1) + (e2 + e3);
#pragma unroll
    for (int d = 32; d >= 1; d >>= 1) s += __shfl_xor(s, d);
    if ((tid & 63) == 0) red[4 + (tid >> 6)] = s;
  }
  __syncthreads();
  if (tid < 256) {
    s = (red[4] + red[5]) + (red[6] + red[7]);
    const float inv = 1.0f / s;
    float4 o;
    o.x = e0 * inv; o.y = e1 * inv; o.z = e2 * inv; o.w = e3 * inv;
    ((float4*)(out + (size_t)b * SS))[tid] = o;
  }
}

extern "C" void kernel_launch(void* const* d_in, const int* in_sizes, int n_in,
                              void* d_out, int out_size, void* d_ws, size_t ws_size,
                              hipStream_t stream) {
  const float* x         = (const float*)d_in[0];
  const float* h_state   = (const float*)d_in[1];
  const float* W_ih0     = (const float*)d_in[2];
  const float* W_ih_rest = (const float*)d_in[3];
  const float* W_hh      = (const float*)d_in[4];
  const float* b_ih      = (const float*)d_in[5];
  const float* b_hh      = (const float*)d_in[6];
  const float* fc_w      = (const float*)d_in[7];
  const float* fc_b      = (const float*)d_in[8];
  float* out = (float*)d_out;

  hipLaunchKernelGGL(rnn_kernel, dim3(BB), dim3(512), 0, stream,
                     x, h_state, W_ih0, W_ih_rest, W_hh, b_ih, b_hh,
                     fc_w, fc_b, out);
}